// Round 1
// baseline (147.174 us; speedup 1.0000x reference)
//
#include <hip/hip_runtime.h>
#include <math.h>

// Problem constants (fixed by setup_inputs): B=8, C=4, H=W=64, K=8192
#define N_POINTS 32768   // B*H*W
#define KCODES   8192
#define HW       4096
#define CHW      16384
#define NWAVES   8                  // waves per block = code slices
#define SLICE    (KCODES / NWAVES)  // 1024 codes per wave
#define CHUNK    8                  // codes per scalar-load chunk

// ws layout (bytes):
//   cb2  float4[8192] @ 0       (2*codebook — exact doubling)
//   cbn  float [8192] @ 131072  (|c|^2, numpy rounding order; 16B aligned)
#define WS_CB2 0
#define WS_CBN 131072

// Bit-exact conv z = W x + b, numpy sequential c-order, no FMA contraction.
__device__ __forceinline__ void compute_z(
    const float* __restrict__ ze, const float* __restrict__ w,
    const float* __restrict__ bias, int n, float zo[4], float& zz) {
  int b = n >> 12, hw = n & 4095;
  const float* p = ze + b * CHW + hw;
  float x0 = p[0], x1 = p[HW], x2 = p[2 * HW], x3 = p[3 * HW];
#pragma unroll
  for (int o = 0; o < 4; ++o) {
    float acc = __fmul_rn(x0, w[o * 4 + 0]);
    acc = __fadd_rn(acc, __fmul_rn(x1, w[o * 4 + 1]));
    acc = __fadd_rn(acc, __fmul_rn(x2, w[o * 4 + 2]));
    acc = __fadd_rn(acc, __fmul_rn(x3, w[o * 4 + 3]));
    zo[o] = __fadd_rn(acc, bias[o]);
  }
  float s = __fmul_rn(zo[0], zo[0]);
  s = __fadd_rn(s, __fmul_rn(zo[1], zo[1]));
  s = __fadd_rn(s, __fmul_rn(zo[2], zo[2]));
  s = __fadd_rn(s, __fmul_rn(zo[3], zo[3]));
  zz = s;
}

// ---------------- Kernel P: codebook transform + loss zero -----------------
// No packed-poison needed anymore (reduction is intra-block in vq_main).
__global__ __launch_bounds__(256) void vq_prep(
    const float* __restrict__ cb, float4* __restrict__ cb2,
    float* __restrict__ cbn, float* __restrict__ out) {
  int t = blockIdx.x * 256 + threadIdx.x;   // grid covers 8192 exactly
  float c0 = cb[t * 4 + 0], c1 = cb[t * 4 + 1];
  float c2 = cb[t * 4 + 2], c3 = cb[t * 4 + 3];
  // doubling by 2 is exact: sum(2*z*c) == 2*sum(z*c) bitwise
  cb2[t] = make_float4(2.f * c0, 2.f * c1, 2.f * c2, 2.f * c3);
  float s = __fmul_rn(c0, c0);
  s = __fadd_rn(s, __fmul_rn(c1, c1));
  s = __fadd_rn(s, __fmul_rn(c2, c2));
  s = __fadd_rn(s, __fmul_rn(c3, c3));
  cbn[t] = s;
  if (t == 0) out[N_POINTS * 4] = 0.f;      // zero the q_loss slot
}

// ---------------- Kernel M: fused conv + argmin + gather + loss ------------
// Structure: 512 blocks x 512 threads. Block owns 64 points (lane<->point);
// wave wv scans code slice [1024*wv, 1024*wv+1024) for those points.
//  - Codes enter via wave-uniform loads (SMEM broadcast): zero VALU staging
//    ops, no ds_read, no in-loop barrier -> inner loop is the pure bit-exact
//    12-op/pair stream.
//  - Grid is exactly 2 blocks/CU = 16 waves/CU (4/SIMD): uniform-length
//    waves, full TLP for dep-chain + scalar-load latency hiding.
//  - Cross-slice argmin reduced via 4KB LDS u64 packed min (first-min
//    semantics identical to the old global atomicMin), finish fused inline.
__global__ __launch_bounds__(512, 4) void vq_main(
    const float* __restrict__ ze, const float* __restrict__ w,
    const float* __restrict__ bias, const float* __restrict__ cb,
    const float4* __restrict__ cb2, const float* __restrict__ cbn,
    float* __restrict__ out) {
  int tid  = threadIdx.x;
  int lane = tid & 63;
  int wv   = __builtin_amdgcn_readfirstlane(tid >> 6);  // wave id 0..7
  int n    = blockIdx.x * 64 + lane;                    // this lane's point

  float z[4], zz;
  compute_z(ze, w, bias, n, z, zz);   // redundant per wave: 0.3% of pair work

  const float4* cseg = cb2 + (wv << 10);   // wave-uniform slice base
  const float*  nseg = cbn + (wv << 10);
  int kbase = wv << 10;
  float best = INFINITY;
  int bidx = 0;

  for (int kc = 0; kc < SLICE; kc += CHUNK) {
    // wave-uniform loads -> scalar cache broadcast (SGPRs), off the VALU pipe
    float4 cc[CHUNK];
    float  cn[CHUNK];
#pragma unroll
    for (int j = 0; j < CHUNK; ++j) cc[j] = cseg[kc + j];
#pragma unroll
    for (int j = 0; j < CHUNK; ++j) cn[j] = nseg[kc + j];
#pragma unroll
    for (int j = 0; j < CHUNK; ++j) {
      // 2*dot with numpy's sequential rounding order (doubling is exact)
      float d = __fmul_rn(z[0], cc[j].x);
      d = __fadd_rn(d, __fmul_rn(z[1], cc[j].y));
      d = __fadd_rn(d, __fmul_rn(z[2], cc[j].z));
      d = __fadd_rn(d, __fmul_rn(z[3], cc[j].w));
      // ref: (|z|^2 - 2*dot) + |c|^2, left-to-right
      float s = __fadd_rn(__fsub_rn(zz, d), cn[j]);
      // ascending k + strict < = first-min within the slice
      if (s < best) { best = s; bidx = kbase + kc + j; }
    }
  }

  // pack (sortable float, k): u64 min == (min value, then min k) across waves
  unsigned int u  = __float_as_uint(best);
  unsigned int so = (u & 0x80000000u) ? ~u : (u | 0x80000000u);
  unsigned long long key =
      ((unsigned long long)so << 32) | (unsigned int)bidx;

  __shared__ unsigned long long red[NWAVES][64];
  red[wv][lane] = key;
  __syncthreads();

  if (tid < 64) {   // wave 0 finishes its 64 points (z still live in regs)
    unsigned long long m = red[0][lane];
#pragma unroll
    for (int i = 1; i < NWAVES; ++i) {
      unsigned long long v = red[i][lane];
      if (v < m) m = v;
    }
    int idx = (int)(unsigned int)(m & 0xFFFFFFFFull);
    float4 c = ((const float4*)cb)[idx];  // bit-exact gather (16B aligned)
    int b = n >> 12, hw = n & 4095;
    float* o = out + b * CHW + hw;
    o[0] = c.x; o[HW] = c.y; o[2 * HW] = c.z; o[3 * HW] = c.w;
    float d0 = c.x - z[0], d1 = c.y - z[1];
    float d2 = c.z - z[2], d3 = c.w - z[3];
    float e = d0 * d0 + d1 * d1 + d2 * d2 + d3 * d3;
#pragma unroll
    for (int off = 32; off > 0; off >>= 1) e += __shfl_down(e, off, 64);
    // q_loss = (1 + BETA) * mean over 131072 elements
    if (lane == 0) atomicAdd(out + (N_POINTS * 4), e * (1.25f / 131072.f));
  }
}

extern "C" void kernel_launch(void* const* d_in, const int* in_sizes, int n_in,
                              void* d_out, int out_size, void* d_ws, size_t ws_size,
                              hipStream_t stream) {
  const float* ze   = (const float*)d_in[0];  // z_e_in [8,4,64,64]
  const float* w    = (const float*)d_in[1];  // pq_w [4,4]
  const float* bias = (const float*)d_in[2];  // pq_b [4]
  const float* cb   = (const float*)d_in[3];  // codebook [8192,4]

  char* ws = (char*)d_ws;
  float4* cb2 = (float4*)(ws + WS_CB2);
  float*  cbn = (float*)(ws + WS_CBN);
  float* out = (float*)d_out;

  vq_prep<<<32, 256, 0, stream>>>(cb, cb2, cbn, out);
  vq_main<<<N_POINTS / 64, 512, 0, stream>>>(ze, w, bias, cb, cb2, cbn, out);
}